// Round 6
// baseline (115.193 us; speedup 1.0000x reference)
//
#include <hip/hip_runtime.h>
#include <hip/hip_fp16.h>

// B=4, S=512, D=256, UNITS=128. out: [B,S,D] fp32.
#define SEQ 512
#define DIM 256
#define UN  128
#define BSZ 2048                       // B*S
#define CSC 2.8853900817779268f        // 2*log2(e)

struct h8 { __half2 a, b, c, d; };     // 16B = 8 f16

static __device__ __forceinline__ unsigned short f2bf(float x) {  // RNE, x>0 finite
  unsigned u = __float_as_uint(x);
  u += 0x7FFF + ((u >> 16) & 1);
  return (unsigned short)(u >> 16);
}
static __device__ __forceinline__ float bf2f(unsigned short s) {
  return __uint_as_float((unsigned)s << 16);
}

// ---- proj: Eq = exp2(CSC*(values@Wq)) [BSZ][UN] fp32,
//            Ev = bf16(exp2(CSC*(values@Wv)))^T [UN][BSZ],
//            Vf16 = f16(values) [BSZ][DIM]
__global__ __launch_bounds__(256) void proj_kernel(
    const float* __restrict__ values, const float* __restrict__ Wq,
    const float* __restrict__ Wv, float* __restrict__ Eq,
    unsigned short* __restrict__ Ev, __half* __restrict__ Vf16) {
  __shared__ float vsm[4 * DIM];
  const int t = threadIdx.x;
  const int r0 = blockIdx.x * 4;
  {
    const int row = t >> 6, c4 = (t & 63) * 4;
    const float4 v = *(const float4*)(values + (r0 + row) * DIM + c4);
    *(float4*)&vsm[row * DIM + c4] = v;
    __half2* vf = (__half2*)(Vf16 + (r0 + row) * DIM + c4);
    vf[0] = __floats2half2_rn(v.x, v.y);
    vf[1] = __floats2half2_rn(v.z, v.w);
  }
  __syncthreads();
  const int half = t >> 7, u = t & 127;
  const float* __restrict__ W = half ? Wv : Wq;
  float acc[4] = {0.f, 0.f, 0.f, 0.f};
  for (int d = 0; d < DIM; d += 4) {
    const float w0 = W[(d + 0) * UN + u], w1 = W[(d + 1) * UN + u];
    const float w2 = W[(d + 2) * UN + u], w3 = W[(d + 3) * UN + u];
#pragma unroll
    for (int k = 0; k < 4; ++k) {
      const float4 v = *(const float4*)&vsm[k * DIM + d];
      acc[k] = fmaf(v.x, w0, acc[k]);
      acc[k] = fmaf(v.y, w1, acc[k]);
      acc[k] = fmaf(v.z, w2, acc[k]);
      acc[k] = fmaf(v.w, w3, acc[k]);
    }
  }
  if (!half) {
#pragma unroll
    for (int k = 0; k < 4; ++k)
      Eq[(r0 + k) * UN + u] = __builtin_amdgcn_exp2f(acc[k] * CSC);
  } else {
    ushort4 o;
    o.x = f2bf(__builtin_amdgcn_exp2f(acc[0] * CSC));
    o.y = f2bf(__builtin_amdgcn_exp2f(acc[1] * CSC));
    o.z = f2bf(__builtin_amdgcn_exp2f(acc[2] * CSC));
    o.w = f2bf(__builtin_amdgcn_exp2f(acc[3] * CSC));
    *(ushort4*)(Ev + (size_t)u * BSZ + r0) = o;   // 8B aligned (r0%4==0)
  }
}

// ---- attn: ONE ROW per block. 2048 blocks x 4 waves = 8192 waves = 100% grid occupancy.
// Row remap interleaves short/long rows so each dispatch window has constant work.
// tanh eval: d = fma(Eq, Ev, 1); term = Vw * rcp(d).
__global__ __launch_bounds__(256, 8) void attn_kernel(
    const __half* __restrict__ Vf16, const float* __restrict__ Eq,
    const unsigned short* __restrict__ Ev, const float* __restrict__ Vw,
    float* __restrict__ out) {
  __shared__ float sc[SEQ];     // u-half-0 sdot partials -> probs
  __shared__ float scp[SEQ];    // u-half-1 sdot partials
  __shared__ float part[4 * DIM];
  __shared__ float red[8];

  const int t = threadIdx.x;
  const int b = blockIdx.x >> 9;
  const int idx = blockIdx.x & 511;
  const int i = (idx & 1) ? (SEQ - 1 - (idx >> 1)) : (idx >> 1);  // balanced remap
  const int bS = b * SEQ;

  const float* __restrict__ eqr = Eq + (size_t)(bS + i) * UN;   // uniform -> s_load

  // ---- phase A: thread owns j-quad jb=4*(t&127) x u-half (t>>7). Active if jb<=i.
  {
    const int jb = (t & 127) << 2;
    const int u0 = (t >> 7) << 6;
    if (jb <= i) {
      float* __restrict__ so = (t >> 7) ? scp : sc;
      const unsigned short* __restrict__ evp = Ev + (size_t)u0 * BSZ + bS + jb;
      float s0 = 0.f, s1 = 0.f, s2 = 0.f, s3 = 0.f;
      ushort4 ec = *(const ushort4*)evp;   // k=0
#pragma unroll 4
      for (int k = 0; k < 64; ++k) {
        // prefetch next u-row; k=63 overshoots into Vf16 region (valid memory)
        const ushort4 en = *(const ushort4*)(evp + (size_t)(k + 1) * BSZ);
        const float q = eqr[u0 + k], w = Vw[u0 + k];
        s0 = fmaf(w, __builtin_amdgcn_rcpf(fmaf(q, bf2f(ec.x), 1.f)), s0);
        s1 = fmaf(w, __builtin_amdgcn_rcpf(fmaf(q, bf2f(ec.y), 1.f)), s1);
        s2 = fmaf(w, __builtin_amdgcn_rcpf(fmaf(q, bf2f(ec.z), 1.f)), s2);
        s3 = fmaf(w, __builtin_amdgcn_rcpf(fmaf(q, bf2f(ec.w), 1.f)), s3);
        ec = en;
      }
      *(float4*)&so[jb] = make_float4(s0, s1, s2, s3);  // slots > i never read
    }
  }
  __syncthreads();

  // ---- phase B: softmax over sc[0..i], all 256 threads ----
  {
    const int w = t >> 6, l = t & 63;
    const float sA = (t <= i) ? sc[t] + scp[t] : 1e30f;
    const float sB = (t + 256 <= i) ? sc[t + 256] + scp[t + 256] : 1e30f;
    float m = fminf(sA, sB);                      // min sdot == max score
#pragma unroll
    for (int o = 32; o; o >>= 1) m = fminf(m, __shfl_xor(m, o));
    if (l == 0) red[w] = m;
    __syncthreads();
    m = fminf(fminf(red[0], red[1]), fminf(red[2], red[3]));
    float sum = 0.f;
    if (t <= i) {
      const float p = __builtin_amdgcn_exp2f((m - sA) * CSC);
      sc[t] = p; sum += p;
    }
    if (t + 256 <= i) {
      const float p = __builtin_amdgcn_exp2f((m - sB) * CSC);
      sc[t + 256] = p; sum += p;
    }
#pragma unroll
    for (int o = 32; o; o >>= 1) sum += __shfl_xor(sum, o);
    if (l == 0) red[4 + w] = sum;
  }
  __syncthreads();
  const float inv = __builtin_amdgcn_rcpf(red[4] + red[5] + red[6] + red[7]);

  // ---- phase C: f16 values; wave g + lane-half jo -> j === 2g+jo (mod 8); 8 d per lane
  {
    const int g = t >> 6, l = t & 63;
    const int jo = l >> 5, d8 = (l & 31) << 3;
    float a[8];
#pragma unroll
    for (int k = 0; k < 8; ++k) a[k] = 0.f;
    int j = 2 * g + jo;
    if (j <= i) {
      h8 vc = *(const h8*)(Vf16 + (size_t)(bS + j) * DIM + d8);
      for (; j <= i; j += 8) {
        const int jn = (j + 8 <= i) ? j + 8 : i;            // clamped prefetch
        const h8 vn = *(const h8*)(Vf16 + (size_t)(bS + jn) * DIM + d8);
        const float p = sc[j];
        const float2 f0 = __half22float2(vc.a), f1 = __half22float2(vc.b);
        const float2 f2 = __half22float2(vc.c), f3 = __half22float2(vc.d);
        a[0] = fmaf(p, f0.x, a[0]); a[1] = fmaf(p, f0.y, a[1]);
        a[2] = fmaf(p, f1.x, a[2]); a[3] = fmaf(p, f1.y, a[3]);
        a[4] = fmaf(p, f2.x, a[4]); a[5] = fmaf(p, f2.y, a[5]);
        a[6] = fmaf(p, f3.x, a[6]); a[7] = fmaf(p, f3.y, a[7]);
        vc = vn;
      }
    }
#pragma unroll
    for (int k = 0; k < 8; ++k) a[k] += __shfl_xor(a[k], 32);  // fold jo halves
    if (jo == 0) {
      float* __restrict__ pp = &part[g * DIM + d8];
      *(float4*)(pp + 0) = make_float4(a[0], a[1], a[2], a[3]);
      *(float4*)(pp + 4) = make_float4(a[4], a[5], a[6], a[7]);
    }
  }
  __syncthreads();

  // ---- epilogue ----
  out[(size_t)(bS + i) * DIM + t] =
      (part[t] + part[DIM + t] + part[2 * DIM + t] + part[3 * DIM + t]) * inv;
}

extern "C" void kernel_launch(void* const* d_in, const int* in_sizes, int n_in,
                              void* d_out, int out_size, void* d_ws, size_t ws_size,
                              hipStream_t stream) {
  const float* values = (const float*)d_in[0];
  const float* Wq     = (const float*)d_in[1];
  const float* Wv     = (const float*)d_in[2];
  const float* Vw     = (const float*)d_in[3];
  float* out = (float*)d_out;
  float* Eq = (float*)d_ws;                            // [BSZ][UN] fp32, 1 MB
  unsigned short* Ev = (unsigned short*)(Eq + (size_t)BSZ * UN);  // [UN][BSZ] bf16, 512 KB
  __half* Vf16 = (__half*)(Ev + (size_t)UN * BSZ);     // [BSZ][DIM] f16, 1 MB (also A-prefetch spill target)
  proj_kernel<<<dim3(BSZ / 4), 256, 0, stream>>>(values, Wq, Wv, Eq, Ev, Vf16);
  attn_kernel<<<dim3(BSZ), 256, 0, stream>>>(Vf16, Eq, Ev, Vw, out);
}

// Round 7
// 105.299 us; speedup vs baseline: 1.0940x; 1.0940x over previous
//
#include <hip/hip_runtime.h>
#include <hip/hip_fp16.h>

// B=4, S=512, D=256, UNITS=128. out: [B,S,D] fp32.
#define SEQ 512
#define DIM 256
#define UN  128
#define BSZ 2048                       // B*S
#define CSC 2.8853900817779268f        // 2*log2(e)

struct h8 { __half2 a, b, c, d; };     // 16B = 8 f16

static __device__ __forceinline__ unsigned short f2bf(float x) {  // RNE, x>0 finite
  unsigned u = __float_as_uint(x);
  u += 0x7FFF + ((u >> 16) & 1);
  return (unsigned short)(u >> 16);
}
static __device__ __forceinline__ float bf2f(unsigned short s) {
  return __uint_as_float((unsigned)s << 16);
}

// ---- proj: Eq = exp2(CSC*(values@Wq)) [BSZ][UN] fp32,
//            Ev = bf16(exp2(CSC*(values@Wv)))^T [UN][BSZ],
//            Vf16 = f16(values) [BSZ][DIM]
__global__ __launch_bounds__(256) void proj_kernel(
    const float* __restrict__ values, const float* __restrict__ Wq,
    const float* __restrict__ Wv, float* __restrict__ Eq,
    unsigned short* __restrict__ Ev, __half* __restrict__ Vf16) {
  __shared__ float vsm[4 * DIM];
  const int t = threadIdx.x;
  const int r0 = blockIdx.x * 4;
  {
    const int row = t >> 6, c4 = (t & 63) * 4;
    const float4 v = *(const float4*)(values + (r0 + row) * DIM + c4);
    *(float4*)&vsm[row * DIM + c4] = v;
    __half2* vf = (__half2*)(Vf16 + (r0 + row) * DIM + c4);
    vf[0] = __floats2half2_rn(v.x, v.y);
    vf[1] = __floats2half2_rn(v.z, v.w);
  }
  __syncthreads();
  const int half = t >> 7, u = t & 127;
  const float* __restrict__ W = half ? Wv : Wq;
  float acc[4] = {0.f, 0.f, 0.f, 0.f};
  for (int d = 0; d < DIM; d += 4) {
    const float w0 = W[(d + 0) * UN + u], w1 = W[(d + 1) * UN + u];
    const float w2 = W[(d + 2) * UN + u], w3 = W[(d + 3) * UN + u];
#pragma unroll
    for (int k = 0; k < 4; ++k) {
      const float4 v = *(const float4*)&vsm[k * DIM + d];
      acc[k] = fmaf(v.x, w0, acc[k]);
      acc[k] = fmaf(v.y, w1, acc[k]);
      acc[k] = fmaf(v.z, w2, acc[k]);
      acc[k] = fmaf(v.w, w3, acc[k]);
    }
  }
  if (!half) {
#pragma unroll
    for (int k = 0; k < 4; ++k)
      Eq[(r0 + k) * UN + u] = __builtin_amdgcn_exp2f(acc[k] * CSC);
  } else {
    ushort4 o;
    o.x = f2bf(__builtin_amdgcn_exp2f(acc[0] * CSC));
    o.y = f2bf(__builtin_amdgcn_exp2f(acc[1] * CSC));
    o.z = f2bf(__builtin_amdgcn_exp2f(acc[2] * CSC));
    o.w = f2bf(__builtin_amdgcn_exp2f(acc[3] * CSC));
    *(ushort4*)(Ev + (size_t)u * BSZ + r0) = o;   // 8B aligned (r0%4==0)
  }
}

// ---- attn: block = (b, pair p), rows {p, S-1-p}; i + jhi = 511 -> constant work.
// tanh eval: d = fma(Eq, Ev, 1); term = Vw * rcp(d).  Depth-4 Ev prefetch.
__global__ __launch_bounds__(256, 4) void attn_kernel(
    const __half* __restrict__ Vf16, const float* __restrict__ Eq,
    const unsigned short* __restrict__ Ev, const float* __restrict__ Vw,
    float* __restrict__ out) {
  __shared__ float sc[2 * SEQ];     // u-half-0 sdot partials -> probs. [lo | hi]
  __shared__ float scp[2 * SEQ];    // u-half-1 sdot partials
  __shared__ float part[8 * DIM];   // ctx partials: [wave g][2 rows][DIM]
  __shared__ float invs[2];

  const int t = threadIdx.x;
  const int b = blockIdx.x >> 8, p = blockIdx.x & 255;
  const int bS = b * SEQ;
  const int i = p;                  // low row: j in [0, i]
  const int ihi = SEQ - 1 - p;      // high row: j in [0, ihi], ihi >= 256
  const int jhi = ihi;

  const float* __restrict__ eql = Eq + (size_t)(bS + i) * UN;    // uniform -> s_load
  const float* __restrict__ eqh = Eq + (size_t)(bS + ihi) * UN;

  // ---- phase A: thread owns j-quad (8B bf16 Ev load) x u-half; depth-4 prefetch ----
  {
    const int qd = t & 127, jb = qd << 2;
    const int u0 = (t >> 7) << 6;
    float* __restrict__ so = (t >> 7) ? scp : sc;
    const unsigned short* __restrict__ evp = Ev + (size_t)u0 * BSZ + bS + jb;
#define LDE(K) (*(const ushort4*)(evp + (size_t)(K) * BSZ))
    if ((t & 64) == 0) {            // waves 0,2: jb < 256 -> dual row
      float h0=0.f,h1=0.f,h2=0.f,h3=0.f,l0=0.f,l1=0.f,l2=0.f,l3=0.f;
      ushort4 e0 = LDE(0), e1 = LDE(1), e2 = LDE(2), e3 = LDE(3);
#define PRD(EC, KK) { \
      const float qh = eqh[u0 + (KK)], ql = eql[u0 + (KK)], w = Vw[u0 + (KK)]; \
      const float f0 = bf2f(EC.x), f1 = bf2f(EC.y), f2 = bf2f(EC.z), f3 = bf2f(EC.w); \
      h0 = fmaf(w, __builtin_amdgcn_rcpf(fmaf(qh, f0, 1.f)), h0); \
      h1 = fmaf(w, __builtin_amdgcn_rcpf(fmaf(qh, f1, 1.f)), h1); \
      h2 = fmaf(w, __builtin_amdgcn_rcpf(fmaf(qh, f2, 1.f)), h2); \
      h3 = fmaf(w, __builtin_amdgcn_rcpf(fmaf(qh, f3, 1.f)), h3); \
      l0 = fmaf(w, __builtin_amdgcn_rcpf(fmaf(ql, f0, 1.f)), l0); \
      l1 = fmaf(w, __builtin_amdgcn_rcpf(fmaf(ql, f1, 1.f)), l1); \
      l2 = fmaf(w, __builtin_amdgcn_rcpf(fmaf(ql, f2, 1.f)), l2); \
      l3 = fmaf(w, __builtin_amdgcn_rcpf(fmaf(ql, f3, 1.f)), l3); }
      for (int k = 0; k < 64; k += 4) {
        // prefetch overshoot (up to Ev row 131) lands in Ev/Vf16 ws region: valid memory
        ushort4 n;
        n = LDE(k + 4); PRD(e0, k + 0); e0 = n;
        n = LDE(k + 5); PRD(e1, k + 1); e1 = n;
        n = LDE(k + 6); PRD(e2, k + 2); e2 = n;
        n = LDE(k + 7); PRD(e3, k + 3); e3 = n;
      }
#undef PRD
      *(float4*)&so[SEQ + jb] = make_float4(h0, h1, h2, h3);
      *(float4*)&so[jb]       = make_float4(l0, l1, l2, l3);  // slots > i never read
    } else if (jb <= jhi) {         // waves 1,3: jb >= 256 -> hi only
      float h0=0.f,h1=0.f,h2=0.f,h3=0.f;
      ushort4 e0 = LDE(0), e1 = LDE(1), e2 = LDE(2), e3 = LDE(3);
#define PRS(EC, KK) { \
      const float qh = eqh[u0 + (KK)], w = Vw[u0 + (KK)]; \
      h0 = fmaf(w, __builtin_amdgcn_rcpf(fmaf(qh, bf2f(EC.x), 1.f)), h0); \
      h1 = fmaf(w, __builtin_amdgcn_rcpf(fmaf(qh, bf2f(EC.y), 1.f)), h1); \
      h2 = fmaf(w, __builtin_amdgcn_rcpf(fmaf(qh, bf2f(EC.z), 1.f)), h2); \
      h3 = fmaf(w, __builtin_amdgcn_rcpf(fmaf(qh, bf2f(EC.w), 1.f)), h3); }
      for (int k = 0; k < 64; k += 4) {
        ushort4 n;
        n = LDE(k + 4); PRS(e0, k + 0); e0 = n;
        n = LDE(k + 5); PRS(e1, k + 1); e1 = n;
        n = LDE(k + 6); PRS(e2, k + 2); e2 = n;
        n = LDE(k + 7); PRS(e3, k + 3); e3 = n;
      }
#undef PRS
      *(float4*)&so[SEQ + jb] = make_float4(h0, h1, h2, h3);  // slots > jhi never read
    }
#undef LDE
  }
  __syncthreads();

  // ---- phase B: softmax, wave0 -> low row, wave1 -> high row, exact ranges ----
  {
    const int w = t >> 6, l = t & 63;
    if (w < 2) {
      const int jmax = (w == 0) ? i : jhi;
      float* __restrict__ r0p = sc + w * SEQ;
      const float* __restrict__ r1p = scp + w * SEQ;
      float m = 1e30f;                           // min sdot == max score
      for (int j = l; j <= jmax; j += 64) m = fminf(m, r0p[j] + r1p[j]);
#pragma unroll
      for (int o = 32; o; o >>= 1) m = fminf(m, __shfl_xor(m, o));
      float sum = 0.f;
      for (int j = l; j <= jmax; j += 64) {
        const float pr = __builtin_amdgcn_exp2f((m - (r0p[j] + r1p[j])) * CSC);
        r0p[j] = pr;
        sum += pr;
      }
#pragma unroll
      for (int o = 32; o; o >>= 1) sum += __shfl_xor(sum, o);
      if (l == 0) invs[w] = __builtin_amdgcn_rcpf(sum);
    }
  }
  __syncthreads();

  // ---- phase C: f16 values, lane covers 8 d; wave g + lane-half jo -> j === 2g+jo (mod 8)
  {
    const int g = t >> 6, l = t & 63;
    const int jo = l >> 5, d8 = (l & 31) << 3;
    float alo[8], ahi[8];
#pragma unroll
    for (int k = 0; k < 8; ++k) { alo[k] = 0.f; ahi[k] = 0.f; }
    int j = 2 * g + jo;                           // j0 <= 7 <= jhi always
    h8 vc = *(const h8*)(Vf16 + (size_t)(bS + j) * DIM + d8);
    float plc = sc[j], phc = sc[SEQ + j];         // plc unused if j > i
    for (; j <= i; j += 8) {                      // both rows share the load
      const int jn = (j + 8 <= jhi) ? j + 8 : jhi;          // clamp: no OOB
      const h8 vn = *(const h8*)(Vf16 + (size_t)(bS + jn) * DIM + d8);
      const float pln = sc[jn], phn = sc[SEQ + jn];
      const float2 f0 = __half22float2(vc.a), f1 = __half22float2(vc.b);
      const float2 f2 = __half22float2(vc.c), f3 = __half22float2(vc.d);
      alo[0] = fmaf(plc, f0.x, alo[0]); alo[1] = fmaf(plc, f0.y, alo[1]);
      alo[2] = fmaf(plc, f1.x, alo[2]); alo[3] = fmaf(plc, f1.y, alo[3]);
      alo[4] = fmaf(plc, f2.x, alo[4]); alo[5] = fmaf(plc, f2.y, alo[5]);
      alo[6] = fmaf(plc, f3.x, alo[6]); alo[7] = fmaf(plc, f3.y, alo[7]);
      ahi[0] = fmaf(phc, f0.x, ahi[0]); ahi[1] = fmaf(phc, f0.y, ahi[1]);
      ahi[2] = fmaf(phc, f1.x, ahi[2]); ahi[3] = fmaf(phc, f1.y, ahi[3]);
      ahi[4] = fmaf(phc, f2.x, ahi[4]); ahi[5] = fmaf(phc, f2.y, ahi[5]);
      ahi[6] = fmaf(phc, f3.x, ahi[6]); ahi[7] = fmaf(phc, f3.y, ahi[7]);
      vc = vn; plc = pln; phc = phn;
    }
    for (; j <= jhi; j += 8) {                    // high row only
      const int jn = (j + 8 <= jhi) ? j + 8 : jhi;
      const h8 vn = *(const h8*)(Vf16 + (size_t)(bS + jn) * DIM + d8);
      const float phn = sc[SEQ + jn];
      const float2 f0 = __half22float2(vc.a), f1 = __half22float2(vc.b);
      const float2 f2 = __half22float2(vc.c), f3 = __half22float2(vc.d);
      ahi[0] = fmaf(phc, f0.x, ahi[0]); ahi[1] = fmaf(phc, f0.y, ahi[1]);
      ahi[2] = fmaf(phc, f1.x, ahi[2]); ahi[3] = fmaf(phc, f1.y, ahi[3]);
      ahi[4] = fmaf(phc, f2.x, ahi[4]); ahi[5] = fmaf(phc, f2.y, ahi[5]);
      ahi[6] = fmaf(phc, f3.x, ahi[6]); ahi[7] = fmaf(phc, f3.y, ahi[7]);
      vc = vn; phc = phn;
    }
#pragma unroll
    for (int k = 0; k < 8; ++k) {                 // fold jo halves (lanes l, l+32)
      alo[k] += __shfl_xor(alo[k], 32);
      ahi[k] += __shfl_xor(ahi[k], 32);
    }
    if (jo == 0) {
      float* __restrict__ plo_ = &part[(g * 2 + 0) * DIM + d8];
      float* __restrict__ phi_ = &part[(g * 2 + 1) * DIM + d8];
      *(float4*)(plo_ + 0) = make_float4(alo[0], alo[1], alo[2], alo[3]);
      *(float4*)(plo_ + 4) = make_float4(alo[4], alo[5], alo[6], alo[7]);
      *(float4*)(phi_ + 0) = make_float4(ahi[0], ahi[1], ahi[2], ahi[3]);
      *(float4*)(phi_ + 4) = make_float4(ahi[4], ahi[5], ahi[6], ahi[7]);
    }
  }
  __syncthreads();

  // ---- epilogue ----
  {
    const float olo = (part[0 * DIM + t] + part[2 * DIM + t] +
                       part[4 * DIM + t] + part[6 * DIM + t]) * invs[0];
    const float ohi = (part[1 * DIM + t] + part[3 * DIM + t] +
                       part[5 * DIM + t] + part[7 * DIM + t]) * invs[1];
    out[(size_t)(bS + i) * DIM + t] = olo;
    out[(size_t)(bS + ihi) * DIM + t] = ohi;
  }
}

extern "C" void kernel_launch(void* const* d_in, const int* in_sizes, int n_in,
                              void* d_out, int out_size, void* d_ws, size_t ws_size,
                              hipStream_t stream) {
  const float* values = (const float*)d_in[0];
  const float* Wq     = (const float*)d_in[1];
  const float* Wv     = (const float*)d_in[2];
  const float* Vw     = (const float*)d_in[3];
  float* out = (float*)d_out;
  float* Eq = (float*)d_ws;                            // [BSZ][UN] fp32, 1 MB
  unsigned short* Ev = (unsigned short*)(Eq + (size_t)BSZ * UN);  // [UN][BSZ] bf16, 512 KB
  __half* Vf16 = (__half*)(Ev + (size_t)UN * BSZ);     // [BSZ][DIM] f16, 1 MB (also A-prefetch overshoot target)
  proj_kernel<<<dim3(BSZ / 4), 256, 0, stream>>>(values, Wq, Wv, Eq, Ev, Vf16);
  attn_kernel<<<dim3(4 * 256), 256, 0, stream>>>(Vf16, Eq, Ev, Vw, out);
}